// Round 4
// baseline (264.051 us; speedup 1.0000x reference)
//
#include <hip/hip_runtime.h>
#include <hip/hip_bf16.h>

#define NB   8
#define NS   5
#define NQ   128
#define TT   16
#define DD   2048
#define NROW 1024               // B*nq
#define NSROW (NB * NS * TT)    // 640 supp rows
#define NQROW (NROW * TT)       // 16384 query rows
#define TOTROW (NSROW + NQROW)  // 17024
#define KQ   512                // quarter-K columns per pipeline stage
#define LDB  1032               // path-B half-K LDS row stride in shorts (+8 pad)
#define LAMI 10.0f
#define LAMF 0.1f

typedef __attribute__((ext_vector_type(8))) short  short8;
typedef __attribute__((ext_vector_type(4))) float  float4v;

// single-instruction packed f32x2 -> bf16x2 (RNE), lo = x
static __device__ __forceinline__ unsigned int cvtpk(float x, float y) {
    unsigned int r;
    asm("v_cvt_pk_bf16_f32 %0, %1, %2" : "=v"(r) : "v"(x), "v"(y));
    return r;
}

// lane i <- lane i-1 across the whole wave (lane 0 <- 0). 1 VALU op, no LDS.
static __device__ __forceinline__ float dpp_shr1(float x) {
    int r = __builtin_amdgcn_update_dpp(0, __builtin_bit_cast(int, x),
                                        0x138 /*wave_shr:1*/, 0xF, 0xF, true);
    return __builtin_bit_cast(float, r);
}

typedef __attribute__((address_space(1))) const unsigned int gu32;
typedef __attribute__((address_space(3))) unsigned int       lu32;
// async global->LDS, 16B/lane; LDS dest = wave-uniform base + lane*16 (HW rule)
static __device__ __forceinline__ void gload_lds16(const unsigned short* g, unsigned short* l) {
    __builtin_amdgcn_global_load_lds((gu32*)g, (lu32*)l, 16, 0, 0);
}

// ---- shared tail: DTW (verified in r2) + tam + fused CE term ----
static __device__ __forceinline__ void
dtw_tail(float (*distS)[TT][TT], float* tamv, int tid, int blk,
         const int* __restrict__ ys, float* __restrict__ out)
{
    const int wave = tid >> 6, lane = tid & 63;
    if (wave < NS && (lane & 31) <= 17) {
        const int g    = lane & 31;
        const int dir  = lane >> 5;
        const int s    = wave;
        const bool isb = (g == 1) | (g == 17);   // band-edge: 3-way softmin
        float val = 0.f, vprev = 0.f;
        #pragma unroll
        for (int t = 1; t <= 32; ++t) {
            float left = dpp_shr1(val);
            float diag = dpp_shr1(vprev);
            int l = t - g;
            if (g >= 1 && l >= 0 && l <= 15) {
                float d = 0.f;
                if (g <= 16) d = dir ? distS[s][15 - l][16 - g] : distS[s][l][g - 1];
                float nv;
                if (l == 0) {
                    nv = left + d;
                } else {
                    float am = -LAMI * diag, bm = -LAMI * left;
                    float mx = fmaxf(am, bm);
                    float s3 = 0.f;
                    if (isb) {
                        float cm = -LAMI * val;
                        float m3 = fmaxf(mx, cm);
                        s3 = __expf(cm - m3);
                        mx = m3;
                    }
                    float ssum = __expf(am - mx) + __expf(bm - mx) + s3;
                    nv = fmaf(-LAMF, mx + __logf(ssum), d);
                }
                vprev = val; val = nv;
            }
        }
        if (g == 17) tamv[s * 2 + dir] = val;
    }
    __syncthreads();

    if (tid < NS) out[1 + blk * NS + tid] = 0.5f * (tamv[2 * tid] + tamv[2 * tid + 1]);
    if (tid == 0) {
        float t1v[NS], t2v[NS];
        #pragma unroll
        for (int s = 0; s < NS; ++s) { t1v[s] = tamv[2 * s]; t2v[s] = tamv[2 * s + 1]; }
        const int y = ys[blk];
        float mx1 = -t1v[0], mx2 = -t2v[0];
        #pragma unroll
        for (int s = 1; s < NS; ++s) { mx1 = fmaxf(mx1, -t1v[s]); mx2 = fmaxf(mx2, -t2v[s]); }
        float s1 = 0.f, s2 = 0.f;
        #pragma unroll
        for (int s = 0; s < NS; ++s) { s1 += __expf(-t1v[s] - mx1); s2 += __expf(-t2v[s] - mx2); }
        float lse1  = mx1 + __logf(s1);
        float lse2v = mx2 + __logf(s2);
        float ty1 = t1v[0], ty2 = t2v[0];
        #pragma unroll
        for (int s = 1; s < NS; ++s) { if (y == s) { ty1 = t1v[s]; ty2 = t2v[s]; } }
        float c = 0.5f * ((lse1 + ty1) + (lse2v + ty2));
        atomicAdd(out, c * (1.0f / (float)NROW));
    }
}

// =============================== PATH A ====================================
// preproc: f32 -> bf16 + row sum-of-squares for supp AND query. One wave/row.
// Query rows written 16B-chunk XOR-swizzled (chunk ^= row&7): dist kernel
// global_load_lds's them LINEARLY and un-swizzles on ds_read (both-sides rule).
__global__ __launch_bounds__(256) void
preproc_all(const float* __restrict__ supp, const float* __restrict__ query,
            unsigned short* __restrict__ suppBf, unsigned short* __restrict__ qBf,
            float* __restrict__ suppSq, float* __restrict__ qSq, float* __restrict__ loss0)
{
    if (blockIdx.x == 0 && threadIdx.x == 0) loss0[0] = 0.f;
    const int wave = threadIdx.x >> 6, lane = threadIdx.x & 63;
    const int row = blockIdx.x * 4 + wave;           // 0..17023
    float ss = 0.f;
    if (row < NSROW) {
        const float* src = supp + (size_t)row * DD;
        unsigned short* dst = suppBf + (size_t)row * DD;   // linear (A read per-lane)
        #pragma unroll
        for (int i = 0; i < 8; ++i) {
            float4 v = *reinterpret_cast<const float4*>(src + i * 256 + lane * 4);
            uint2 pv = { cvtpk(v.x, v.y), cvtpk(v.z, v.w) };
            *reinterpret_cast<uint2*>(dst + i * 256 + lane * 4) = pv;
            ss += v.x * v.x + v.y * v.y + v.z * v.z + v.w * v.w;
        }
    } else {
        const int qrow = row - NSROW;
        const float* src = query + (size_t)qrow * DD;
        unsigned short* dst = qBf + (size_t)qrow * DD;
        const int swz = qrow & 7;
        #pragma unroll
        for (int i = 0; i < 8; ++i) {
            float4 v = *reinterpret_cast<const float4*>(src + i * 256 + lane * 4);
            uint2 pv = { cvtpk(v.x, v.y), cvtpk(v.z, v.w) };
            int c8 = i * 32 + (lane >> 1);               // logical 16B chunk 0..255
            *reinterpret_cast<uint2*>(dst + ((c8 ^ swz) * 8 + (lane & 1) * 4)) = pv;
            ss += v.x * v.x + v.y * v.y + v.z * v.z + v.w * v.w;
        }
    }
    #pragma unroll
    for (int off = 32; off >= 1; off >>= 1) ss += __shfl_xor(ss, off, 64);
    if (lane == 0) { if (row < NSROW) suppSq[row] = ss; else qSq[row - NSROW] = ss; }
}

// One block per (b,q). Staging = 2 async global_load_lds issues/thread/quarter
// (no cvt, no sumsq, no ds_write, no VGPR round-trip -> cannot spill).
// Quarter-K double buffer: issue next ∥ MFMA current. A direct from L2-hot suppBf.
__global__ __launch_bounds__(512, 8) void
dist_dtw_qbf(const unsigned short* __restrict__ suppBf, const unsigned short* __restrict__ qBf,
             const float* __restrict__ suppSq, const float* __restrict__ qSq,
             const int* __restrict__ ys, float* __restrict__ out)
{
    __shared__ __align__(16) unsigned short sB[2][TT * KQ];  // 2 x 16 KB
    __shared__ float ssq[96];
    __shared__ float distS[NS][TT][TT];
    __shared__ float tamv[16];

    const int tid  = threadIdx.x;
    const int blk  = blockIdx.x;          // b*128 + q
    const int wave = tid >> 6;            // 0..7 (0..4 = s)
    const int lane = tid & 63;
    const int fr   = lane & 15;
    const int quad = lane >> 4;

    const unsigned short* qt = qBf + (size_t)blk * TT * DD;  // this block's 64 KB tile

    if (tid < 80)       ssq[tid] = suppSq[(blk >> 7) * (NS * TT) + tid];
    else if (tid < 96)  ssq[tid] = qSq[blk * TT + (tid - 80)];

    // stage quarter p into buf: wave w covers rows {w, w+8}; fully coalesced.
    auto stage = [&](int p, int buf) {
        #pragma unroll
        for (int j = 0; j < 2; ++j) {
            int r = wave + j * 8;
            gload_lds16(qt + (size_t)r * DD + p * KQ + lane * 8, &sB[buf][r * KQ]);
        }
    };

    stage(0, 0);
    __syncthreads();   // vmcnt drain at barrier -> buf0 ready

    float4v acc0 = {0.f, 0.f, 0.f, 0.f}, acc1 = {0.f, 0.f, 0.f, 0.f};
    const unsigned short* ap =
        suppBf + ((size_t)((blk >> 7) * NS + wave) * TT + fr) * DD + quad * 8;
    const int swzB = (fr & 7) * 8;       // un-swizzle XOR (short units)

    #pragma unroll
    for (int p = 0; p < 4; ++p) {
        if (p < 3) stage(p + 1, (p + 1) & 1);   // issue next quarter under MFMA
        if (wave < NS) {
            const unsigned short* a  = ap + p * KQ;
            const unsigned short* bb = &sB[p & 1][fr * KQ];
            #pragma unroll
            for (int kk = 0; kk < 16; kk += 2) {
                short8 a0 = *reinterpret_cast<const short8*>(a + kk * 32);
                short8 a1 = *reinterpret_cast<const short8*>(a + kk * 32 + 32);
                short8 b0 = *reinterpret_cast<const short8*>(bb + ((kk * 32      + quad * 8) ^ swzB));
                short8 b1 = *reinterpret_cast<const short8*>(bb + ((kk * 32 + 32 + quad * 8) ^ swzB));
                acc0 = __builtin_amdgcn_mfma_f32_16x16x32_bf16(a0, b0, acc0, 0, 0, 0);
                acc1 = __builtin_amdgcn_mfma_f32_16x16x32_bf16(a1, b1, acc1, 0, 0, 0);
            }
        }
        __syncthreads();   // MFMA reads done + next quarter's loads drained
    }

    if (wave < NS) {
        float qn = sqrtf(ssq[80 + fr]);
        #pragma unroll
        for (int r = 0; r < 4; ++r) {
            int l = quad * 4 + r;
            float denom = fmaxf(sqrtf(ssq[wave * 16 + l]) * qn, 1e-8f);
            distS[wave][l][fr] = 1.0f - (acc0[r] + acc1[r]) / denom;
        }
    }
    __syncthreads();

    dtw_tail(distS, tamv, tid, blk, ys, out);
}

// =============================== PATH B ====================================
// Fallback (ws too small for qBf): round-1 proven structure + cvtpk + new DTW.
__global__ __launch_bounds__(256) void
preproc_supp(const float* __restrict__ supp, unsigned short* __restrict__ suppBf,
             float* __restrict__ suppSq, float* __restrict__ loss0)
{
    if (blockIdx.x == 0 && threadIdx.x == 0) loss0[0] = 0.f;
    const int wave = threadIdx.x >> 6, lane = threadIdx.x & 63;
    const int row = blockIdx.x * 4 + wave;           // 0..639
    const float* src = supp + (size_t)row * DD;
    unsigned short* dst = suppBf + (size_t)row * DD;
    float ss = 0.f;
    #pragma unroll
    for (int i = 0; i < 8; ++i) {
        float4 v = *reinterpret_cast<const float4*>(src + i * 256 + lane * 4);
        uint2 pv = { cvtpk(v.x, v.y), cvtpk(v.z, v.w) };
        *reinterpret_cast<uint2*>(dst + i * 256 + lane * 4) = pv;
        ss += v.x * v.x + v.y * v.y + v.z * v.z + v.w * v.w;
    }
    #pragma unroll
    for (int off = 32; off >= 1; off >>= 1) ss += __shfl_xor(ss, off, 64);
    if (lane == 0) suppSq[row] = ss;
}

__global__ __launch_bounds__(512, 8) void
dist_dtw_stage(const unsigned short* __restrict__ suppBf, const float* __restrict__ suppSq,
               const float* __restrict__ query, const int* __restrict__ ys,
               float* __restrict__ out)
{
    __shared__ __align__(16) unsigned short sB[TT * LDB];   // 33024 B (half-K tile)
    __shared__ float ssq[96];
    __shared__ float distS[NS][TT][TT];
    __shared__ float tamv[16];

    const int tid  = threadIdx.x;
    const int blk  = blockIdx.x;
    const int wave = tid >> 6;
    const int lane = tid & 63;
    const int fr   = lane & 15;
    const int quad = lane >> 4;

    const int qr = tid >> 5;
    const int qc = tid & 31;
    const float* qsrc = query + (size_t)(blk * TT + qr) * DD;

    {   // stage K-half 0
        float ss = 0.f;
        #pragma unroll
        for (int i = 0; i < 8; ++i) {
            float4 v = *reinterpret_cast<const float4*>(qsrc + (qc + i * 32) * 4);
            uint2 pv = { cvtpk(v.x, v.y), cvtpk(v.z, v.w) };
            *reinterpret_cast<uint2*>(&sB[qr * LDB + (qc + i * 32) * 4]) = pv;
            ss += v.x * v.x + v.y * v.y + v.z * v.z + v.w * v.w;
        }
        #pragma unroll
        for (int off = 16; off >= 1; off >>= 1) ss += __shfl_xor(ss, off, 32);
        if (qc == 0) ssq[80 + qr] = ss;
        if (tid < 80) ssq[tid] = suppSq[(blk >> 7) * (NS * TT) + tid];
    }
    __syncthreads();

    float4v acc0 = {0.f, 0.f, 0.f, 0.f}, acc1 = {0.f, 0.f, 0.f, 0.f};
    const unsigned short* ap =
        suppBf + ((size_t)((blk >> 7) * NS + wave) * TT + fr) * DD + quad * 8;
    const unsigned short* bp = &sB[fr * LDB + quad * 8];
    if (wave < NS) {
        #pragma unroll 8
        for (int k = 0; k < 32; k += 2) {
            short8 a0 = *reinterpret_cast<const short8*>(ap + k * 32);
            short8 a1 = *reinterpret_cast<const short8*>(ap + k * 32 + 32);
            short8 b0 = *reinterpret_cast<const short8*>(bp + k * 32);
            short8 b1 = *reinterpret_cast<const short8*>(bp + k * 32 + 32);
            acc0 = __builtin_amdgcn_mfma_f32_16x16x32_bf16(a0, b0, acc0, 0, 0, 0);
            acc1 = __builtin_amdgcn_mfma_f32_16x16x32_bf16(a1, b1, acc1, 0, 0, 0);
        }
    }
    __syncthreads();

    {   // stage K-half 1
        float ss = 0.f;
        #pragma unroll
        for (int i = 0; i < 8; ++i) {
            float4 v = *reinterpret_cast<const float4*>(qsrc + 1024 + (qc + i * 32) * 4);
            uint2 pv = { cvtpk(v.x, v.y), cvtpk(v.z, v.w) };
            *reinterpret_cast<uint2*>(&sB[qr * LDB + (qc + i * 32) * 4]) = pv;
            ss += v.x * v.x + v.y * v.y + v.z * v.z + v.w * v.w;
        }
        #pragma unroll
        for (int off = 16; off >= 1; off >>= 1) ss += __shfl_xor(ss, off, 32);
        if (qc == 0) ssq[80 + qr] += ss;
    }
    __syncthreads();

    if (wave < NS) {
        #pragma unroll 8
        for (int k = 32; k < 64; k += 2) {
            short8 a0 = *reinterpret_cast<const short8*>(ap + k * 32);
            short8 a1 = *reinterpret_cast<const short8*>(ap + k * 32 + 32);
            short8 b0 = *reinterpret_cast<const short8*>(bp + (k - 32) * 32);
            short8 b1 = *reinterpret_cast<const short8*>(bp + (k - 32) * 32 + 32);
            acc0 = __builtin_amdgcn_mfma_f32_16x16x32_bf16(a0, b0, acc0, 0, 0, 0);
            acc1 = __builtin_amdgcn_mfma_f32_16x16x32_bf16(a1, b1, acc1, 0, 0, 0);
        }
        float qn = sqrtf(ssq[80 + fr]);
        #pragma unroll
        for (int r = 0; r < 4; ++r) {
            int l = quad * 4 + r;
            float denom = fmaxf(sqrtf(ssq[wave * 16 + l]) * qn, 1e-8f);
            distS[wave][l][fr] = 1.0f - (acc0[r] + acc1[r]) / denom;
        }
    }
    __syncthreads();

    dtw_tail(distS, tamv, tid, blk, ys, out);
}

extern "C" void kernel_launch(void* const* d_in, const int* in_sizes, int n_in,
                              void* d_out, int out_size, void* d_ws, size_t ws_size,
                              hipStream_t stream) {
    const float* supp  = (const float*)d_in[0];
    const float* query = (const float*)d_in[1];
    const int*   ys    = (const int*)d_in[2];
    float* out = (float*)d_out;

    float* suppSq = (float*)d_ws;
    float* qSq    = suppSq + NSROW;
    unsigned short* suppBf_A = (unsigned short*)(qSq + NQROW);
    unsigned short* qBf      = suppBf_A + (size_t)NSROW * DD;

    const size_t needA = (size_t)NSROW * 4 + (size_t)NQROW * 4
                       + (size_t)NSROW * DD * 2 + (size_t)NQROW * DD * 2;  // ~66.6 MiB

    if (ws_size >= needA) {
        preproc_all<<<TOTROW / 4, 256, 0, stream>>>(supp, query, suppBf_A, qBf,
                                                    suppSq, qSq, out);
        dist_dtw_qbf<<<NROW, 512, 0, stream>>>(suppBf_A, qBf, suppSq, qSq, ys, out);
    } else {
        // compact layout: suppSq + suppBf only (~2.62 MB)
        unsigned short* suppBf_B = (unsigned short*)(suppSq + NSROW);
        preproc_supp<<<NSROW / 4, 256, 0, stream>>>(supp, suppBf_B, suppSq, out);
        dist_dtw_stage<<<NROW, 512, 0, stream>>>(suppBf_B, suppSq, query, ys, out);
    }
}

// Round 5
// 229.831 us; speedup vs baseline: 1.1489x; 1.1489x over previous
//
#include <hip/hip_runtime.h>
#include <hip/hip_bf16.h>

#define NB   8
#define NS   5
#define NQ   128
#define TT   16
#define DD   2048
#define NROW 1024               // B*nq
#define NSROW (NB * NS * TT)    // 640 supp rows
#define KSL  512                // per-wave K slice (DD/4)
#define LAMI 10.0f
#define LAMF 0.1f

typedef __attribute__((ext_vector_type(8))) short  short8;
typedef __attribute__((ext_vector_type(4))) float  float4v;

// single-instruction packed f32x2 -> bf16x2 (RNE), lo = x
static __device__ __forceinline__ unsigned int cvtpk(float x, float y) {
    unsigned int r;
    asm("v_cvt_pk_bf16_f32 %0, %1, %2" : "=v"(r) : "v"(x), "v"(y));
    return r;
}

// lane i <- lane i-1 across the whole wave (lane 0 <- 0). 1 VALU op, no LDS.
static __device__ __forceinline__ float dpp_shr1(float x) {
    int r = __builtin_amdgcn_update_dpp(0, __builtin_bit_cast(int, x),
                                        0x138 /*wave_shr:1*/, 0xF, 0xF, true);
    return __builtin_bit_cast(float, r);
}

// supp only: f32 -> bf16 + row sum-of-squares. One wave per row (640 rows).
// Block 0 thread 0 also zeroes the loss accumulator.
__global__ __launch_bounds__(256) void
preproc_supp(const float* __restrict__ supp, unsigned short* __restrict__ suppBf,
             float* __restrict__ suppSq, float* __restrict__ loss0)
{
    if (blockIdx.x == 0 && threadIdx.x == 0) loss0[0] = 0.f;
    const int wave = threadIdx.x >> 6, lane = threadIdx.x & 63;
    const int row = blockIdx.x * 4 + wave;           // 0..639
    const float* src = supp + (size_t)row * DD;
    unsigned short* dst = suppBf + (size_t)row * DD;
    float ss = 0.f;
    #pragma unroll
    for (int i = 0; i < 8; ++i) {
        float4 v = *reinterpret_cast<const float4*>(src + i * 256 + lane * 4);
        uint2 pv = { cvtpk(v.x, v.y), cvtpk(v.z, v.w) };
        *reinterpret_cast<uint2*>(dst + i * 256 + lane * 4) = pv;
        ss += v.x * v.x + v.y * v.y + v.z * v.z + v.w * v.w;
    }
    #pragma unroll
    for (int off = 32; off >= 1; off >>= 1) ss += __shfl_xor(ss, off, 64);
    if (lane == 0) suppSq[row] = ss;
}

// One block per (b,q), 4 waves. Wave w owns K-slice [w*512,(w+1)*512): loads
// query f32 direct->regs (cvt in-reg), supp bf16 from L2, 5 MFMAs/k-step, f32
// sumsq via fma. ZERO barriers / LDS in the K-loop (the round-4 ablation showed
// barrier-drain convoys, not staging work, were the 85 us). Then: one 4-wave
// LDS reduction, DTW as 12 lane-groups of 18 (all 10 (s,dir) problems in ONE
// 32-step pass), fused CE via atomicAdd.
__global__ __launch_bounds__(256, 4) void
dist_dtw_wave(const unsigned short* __restrict__ suppBf, const float* __restrict__ suppSq,
              const float* __restrict__ query, const int* __restrict__ ys,
              float* __restrict__ out)   // out[0]=loss, out+1 = tam (5120 f32)
{
    __shared__ __align__(16) float red[4][NS][64][4];  // 20 KB partial dot tiles
    __shared__ float qsqp[4][16];                      // per-wave q row-sumsq partials
    __shared__ float qq[16];
    __shared__ float distS[NS][TT][TT];                // 5 KB
    __shared__ float ssqS[80];
    __shared__ float tamv[12];

    const int tid  = threadIdx.x;
    const int blk  = blockIdx.x;          // b*128 + q
    const int wave = tid >> 6;            // 0..3 = K-slice
    const int lane = tid & 63;
    const int fr   = lane & 15;
    const int quad = lane >> 4;

    if (tid < 80) ssqS[tid] = suppSq[(blk >> 7) * (NS * TT) + tid];

    // ---- barrier-free K-loop over this wave's 512-column slice ----
    const float* qp = query + (size_t)(blk * TT + fr) * DD + wave * KSL + quad * 8;
    const unsigned short* aps[NS];
    #pragma unroll
    for (int s = 0; s < NS; ++s)
        aps[s] = suppBf + ((size_t)((blk >> 7) * NS + s) * TT + fr) * DD
               + wave * KSL + quad * 8;

    float4v acc[NS];
    #pragma unroll
    for (int s = 0; s < NS; ++s) acc[s] = (float4v){0.f, 0.f, 0.f, 0.f};
    float ss = 0.f;

    #pragma unroll 2
    for (int kk = 0; kk < 16; ++kk) {
        float4 q0 = *reinterpret_cast<const float4*>(qp + kk * 32);
        float4 q1 = *reinterpret_cast<const float4*>(qp + kk * 32 + 4);
        union { unsigned int u[4]; short8 v; } qu;
        qu.u[0] = cvtpk(q0.x, q0.y); qu.u[1] = cvtpk(q0.z, q0.w);
        qu.u[2] = cvtpk(q1.x, q1.y); qu.u[3] = cvtpk(q1.z, q1.w);
        ss += q0.x*q0.x + q0.y*q0.y + q0.z*q0.z + q0.w*q0.w
            + q1.x*q1.x + q1.y*q1.y + q1.z*q1.z + q1.w*q1.w;
        #pragma unroll
        for (int s = 0; s < NS; ++s) {
            short8 a = *reinterpret_cast<const short8*>(aps[s] + kk * 32);
            acc[s] = __builtin_amdgcn_mfma_f32_16x16x32_bf16(a, qu.v, acc[s], 0, 0, 0);
        }
    }

    // per-row f32 sumsq: lanes {fr, fr+16, fr+32, fr+48} hold quad partials
    ss += __shfl_xor(ss, 16, 64);
    ss += __shfl_xor(ss, 32, 64);
    if (lane < 16) qsqp[wave][lane] = ss;
    #pragma unroll
    for (int s = 0; s < NS; ++s)
        *reinterpret_cast<float4v*>(red[wave][s][lane]) = acc[s];
    __syncthreads();

    if (tid < 16) qq[tid] = qsqp[0][tid] + qsqp[1][tid] + qsqp[2][tid] + qsqp[3][tid];
    __syncthreads();

    // ---- reduce 4 wave-partials + cosine epilogue -> distS ----
    for (int p = tid; p < NS * 64; p += 256) {
        int t = p >> 6, ln = p & 63;
        float4v s4 = *reinterpret_cast<const float4v*>(red[0][t][ln]);
        #pragma unroll
        for (int w = 1; w < 4; ++w) {
            float4v r = *reinterpret_cast<const float4v*>(red[w][t][ln]);
            s4[0] += r[0]; s4[1] += r[1]; s4[2] += r[2]; s4[3] += r[3];
        }
        int m = ln & 15, qd = ln >> 4;
        float qn = sqrtf(qq[m]);
        #pragma unroll
        for (int r = 0; r < 4; ++r) {
            int l = qd * 4 + r;
            float denom = fmaxf(sqrtf(ssqS[t * 16 + l]) * qn, 1e-8f);
            distS[t][l][m] = 1.0f - s4[r] / denom;
        }
    }
    __syncthreads();

    // ---- DTW: 12 groups of 18 lanes (4 waves x lanes {0-17,21-38,42-59});
    //      slot = wave*3+grp = s*2+dir; all 10 problems in ONE 32-step pass ----
    {
        const int grp  = lane / 21;             // 3 => unused tail lanes
        const int g    = lane - grp * 21;       // 0..20 within group
        const int slot = wave * 3 + grp;
        float val = 0.f, vprev = 0.f;           // init for ALL lanes (dpp sources)
        if (grp < 3 && slot < 10 && g <= 17) {
            const int s    = slot >> 1;
            const int dir  = slot & 1;
            const bool isb = (g == 1) | (g == 17);
            #pragma unroll
            for (int t = 1; t <= 32; ++t) {
                float left = dpp_shr1(val);
                float diag = dpp_shr1(vprev);
                int l = t - g;
                if (g >= 1 && l >= 0 && l <= 15) {
                    float d = 0.f;
                    if (g <= 16) d = dir ? distS[s][15 - l][16 - g] : distS[s][l][g - 1];
                    float nv;
                    if (l == 0) {
                        nv = left + d;
                    } else {
                        float am = -LAMI * diag, bm = -LAMI * left;
                        float mx = fmaxf(am, bm);
                        float s3 = 0.f;
                        if (isb) {
                            float cm = -LAMI * val;
                            float m3 = fmaxf(mx, cm);
                            s3 = __expf(cm - m3);
                            mx = m3;
                        }
                        float ssum = __expf(am - mx) + __expf(bm - mx) + s3;
                        nv = fmaf(-LAMF, mx + __logf(ssum), d);
                    }
                    vprev = val; val = nv;
                }
            }
            if (g == 17) tamv[slot] = val;
        }
    }
    __syncthreads();

    // ---- outputs: tam + fused per-row cross-entropy term ----
    if (tid < NS) out[1 + blk * NS + tid] = 0.5f * (tamv[2 * tid] + tamv[2 * tid + 1]);
    if (tid == 0) {
        float t1v[NS], t2v[NS];
        #pragma unroll
        for (int s = 0; s < NS; ++s) { t1v[s] = tamv[2 * s]; t2v[s] = tamv[2 * s + 1]; }
        const int y = ys[blk];
        float mx1 = -t1v[0], mx2 = -t2v[0];
        #pragma unroll
        for (int s = 1; s < NS; ++s) { mx1 = fmaxf(mx1, -t1v[s]); mx2 = fmaxf(mx2, -t2v[s]); }
        float s1 = 0.f, s2 = 0.f;
        #pragma unroll
        for (int s = 0; s < NS; ++s) { s1 += __expf(-t1v[s] - mx1); s2 += __expf(-t2v[s] - mx2); }
        float lse1  = mx1 + __logf(s1);
        float lse2v = mx2 + __logf(s2);
        float ty1 = t1v[0], ty2 = t2v[0];
        #pragma unroll
        for (int s = 1; s < NS; ++s) { if (y == s) { ty1 = t1v[s]; ty2 = t2v[s]; } }
        float c = 0.5f * ((lse1 + ty1) + (lse2v + ty2));
        atomicAdd(out, c * (1.0f / (float)NROW));
    }
}

extern "C" void kernel_launch(void* const* d_in, const int* in_sizes, int n_in,
                              void* d_out, int out_size, void* d_ws, size_t ws_size,
                              hipStream_t stream) {
    const float* supp  = (const float*)d_in[0];
    const float* query = (const float*)d_in[1];
    const int*   ys    = (const int*)d_in[2];
    float* out = (float*)d_out;

    // workspace: suppSq (640 f32) + suppBf (2.62 MB) — small, proven-safe size
    float* suppSq = (float*)d_ws;
    unsigned short* suppBf = (unsigned short*)(suppSq + NSROW);

    preproc_supp<<<NSROW / 4, 256, 0, stream>>>(supp, suppBf, suppSq, out);
    dist_dtw_wave<<<NROW, 256, 0, stream>>>(suppBf, suppSq, query, ys, out);
}